// Round 3
// baseline (305.358 us; speedup 1.0000x reference)
//
#include <hip/hip_runtime.h>
#include <math.h>

// ---------------- ws layout (floats) ----------------
// [0]        : loss accumulator
// [1..127]   : sum p*inner  (nodes 0..126)
// [128..254] : sum inner    (nodes 0..126)
// [255]      : pad
// [256 ..)               : logQT [100][256]
// [256+25600 ..)         : Q     [256][100]
// [256+51200 ..)         : p     [8192][256]  (col 255 = pad, never read)

#define OFF_LOGQT 256
#define OFF_Q     (256 + 25600)
#define OFF_P     (256 + 51200)

// ---------------- kernel 0: log_softmax of leaf_params ----------------
__global__ __launch_bounds__(64) void k_logsoftmax(const float* __restrict__ lp,
                                                   float* __restrict__ logQT,
                                                   float* __restrict__ Q)
{
    int r = blockIdx.x;           // leaf 0..255
    int lane = threadIdx.x;       // 0..63
    float v0 = (lane < 100)      ? lp[r * 100 + lane]      : -INFINITY;
    float v1 = (lane + 64 < 100) ? lp[r * 100 + lane + 64] : -INFINITY;
    float m = fmaxf(v0, v1);
    for (int s = 32; s; s >>= 1) m = fmaxf(m, __shfl_xor(m, s));
    float e = 0.f;
    if (lane < 100)      e += expf(v0 - m);
    if (lane + 64 < 100) e += expf(v1 - m);
    for (int s = 32; s; s >>= 1) e += __shfl_xor(e, s);
    float logZ = m + logf(e);
    if (lane < 100) {
        float lq = v0 - logZ;
        Q[r * 100 + lane] = expf(lq);
        logQT[lane * 256 + r] = lq;
    }
    if (lane + 64 < 100) {
        float lq = v1 - logZ;
        Q[r * 100 + lane + 64] = expf(lq);
        logQT[(lane + 64) * 256 + r] = lq;
    }
}

// ---------------- kernel 1: fp32 GEMM + bias + beta + sigmoid ----------------
// logits[i][n] = sum_k x[i][k]*W[n][k] + b[n];  p = sigmoid(beta[n]*logits)
#define BM 64
#define BN 64
#define BK 32

__global__ __launch_bounds__(256) void k_gemm_sig(const float* __restrict__ x,
                                                  const float* __restrict__ W,
                                                  const float* __restrict__ bias,
                                                  const float* __restrict__ beta,
                                                  float* __restrict__ p)
{
    __shared__ float As[BM][BK + 4];   // [64][36]  x tile, row-major
    __shared__ float Bs[BK][BN + 4];   // [32][68]  W tile, transposed to [k][node]
    int tid = threadIdx.x;
    int row0 = blockIdx.x * BM;
    int col0 = blockIdx.y * BN;
    int tx = tid & 15, ty = tid >> 4;
    float acc[4][4] = {};

    for (int k0 = 0; k0 < 2048; k0 += BK) {
#pragma unroll
        for (int i = 0; i < 2; ++i) {
            int idx = tid + i * 256;       // 0..511
            int r = idx >> 3;              // 0..63
            int c4 = idx & 7;              // 0..7 (float4 along k)
            float4 v = *(const float4*)(x + (size_t)(row0 + r) * 2048 + k0 + c4 * 4);
            *(float4*)&As[r][c4 * 4] = v;
            int wr = col0 + r;
            float4 wv = make_float4(0.f, 0.f, 0.f, 0.f);
            if (wr < 255)
                wv = *(const float4*)(W + (size_t)wr * 2048 + k0 + c4 * 4);
            Bs[c4 * 4 + 0][r] = wv.x;
            Bs[c4 * 4 + 1][r] = wv.y;
            Bs[c4 * 4 + 2][r] = wv.z;
            Bs[c4 * 4 + 3][r] = wv.w;
        }
        __syncthreads();
#pragma unroll
        for (int kk = 0; kk < BK; ++kk) {
            float a0 = As[ty * 4 + 0][kk];
            float a1 = As[ty * 4 + 1][kk];
            float a2 = As[ty * 4 + 2][kk];
            float a3 = As[ty * 4 + 3][kk];
            float4 b4 = *(float4*)&Bs[kk][tx * 4];
            acc[0][0] += a0 * b4.x; acc[0][1] += a0 * b4.y; acc[0][2] += a0 * b4.z; acc[0][3] += a0 * b4.w;
            acc[1][0] += a1 * b4.x; acc[1][1] += a1 * b4.y; acc[1][2] += a1 * b4.z; acc[1][3] += a1 * b4.w;
            acc[2][0] += a2 * b4.x; acc[2][1] += a2 * b4.y; acc[2][2] += a2 * b4.z; acc[2][3] += a2 * b4.w;
            acc[3][0] += a3 * b4.x; acc[3][1] += a3 * b4.y; acc[3][2] += a3 * b4.z; acc[3][3] += a3 * b4.w;
        }
        __syncthreads();
    }

#pragma unroll
    for (int i = 0; i < 4; ++i) {
        int gr = row0 + ty * 4 + i;
#pragma unroll
        for (int j = 0; j < 4; ++j) {
            int gc = col0 + tx * 4 + j;
            if (gc < 255) {
                float t = beta[gc] * (acc[i][j] + bias[gc]);
                p[(size_t)gr * 256 + gc] = 1.f / (1.f + expf(-t));
            }
        }
    }
}

// ---------------- kernel 2: tree pass ----------------
// 256 threads = 4 waves; each wave handles 4 rows sequentially (16 rows/block)
__global__ __launch_bounds__(256) void k_tree(const float* __restrict__ p,
                                              const int* __restrict__ labels,
                                              const float* __restrict__ logQT,
                                              const float* __restrict__ Q,
                                              float* __restrict__ accum,
                                              float* __restrict__ out)
{
    __shared__ float psh[4][256];
    __shared__ float accPI[127];
    __shared__ float accI[127];
    __shared__ float loss_sh;
    int tid = threadIdx.x;
    int wave = tid >> 6, lane = tid & 63;
    if (tid < 127) { accPI[tid] = 0.f; accI[tid] = 0.f; }
    if (tid == 255) loss_sh = 0.f;
    __syncthreads();

    for (int rr = 0; rr < 4; ++rr) {
        int b = blockIdx.x * 16 + wave * 4 + rr;
        *(float4*)&psh[wave][lane * 4] = *(const float4*)&p[(size_t)b * 256 + lane * 4];
        __syncthreads();   // make this wave's LDS writes visible to all its lanes

        int label = labels[b];
        float4 tq = *(const float4*)&logQT[(size_t)label * 256 + lane * 4];
        float tqa[4] = {tq.x, tq.y, tq.z, tq.w};

        float lsum = 0.f;
        float best = -1.f;
        int bestIdx = 0;
#pragma unroll
        for (int i = 0; i < 4; ++i) {
            int l = lane * 4 + i;
            float f = 1.f;
#pragma unroll
            for (int d = 0; d < 8; ++d) {
                int j = l >> (8 - d);
                int node = (1 << d) - 1 + j;
                float g = psh[wave][node];
                f *= ((l >> (7 - d)) & 1) ? g : (1.f - g);
            }
            lsum += f * tqa[i];
            if (f > best) { best = f; bestIdx = l; }   // strict > keeps first max
        }
        for (int s = 32; s; s >>= 1) lsum += __shfl_xor(lsum, s);
        for (int s = 32; s; s >>= 1) {
            float ov = __shfl_xor(best, s);
            int   oi = __shfl_xor(bestIdx, s);
            if (ov > best || (ov == best && oi < bestIdx)) { best = ov; bestIdx = oi; }
        }
        if (lane == 0) atomicAdd(&loss_sh, lsum);

        // inner-path sums, only nodes < 127 feed C
#pragma unroll
        for (int t = 0; t < 2; ++t) {
            int n = lane + t * 64;
            if (n < 127) {
                float f = 1.f;
                int cur = n;
                while (cur > 0) {
                    int par = (cur - 1) >> 1;
                    float g = psh[wave][par];
                    f *= (cur == 2 * par + 2) ? g : (1.f - g);
                    cur = par;
                }
                atomicAdd(&accPI[n], psh[wave][n] * f);
                atomicAdd(&accI[n], f);
            }
        }

        // output row = Q[best leaf]
        const float* qrow = Q + (size_t)bestIdx * 100;
        float* orow = out + 1 + (size_t)b * 100;
        orow[lane] = qrow[lane];
        if (lane < 36) orow[64 + lane] = qrow[64 + lane];
        __syncthreads();   // protect psh before next iteration overwrites
    }

    if (tid < 127) {
        atomicAdd(&accum[1 + tid],   accPI[tid]);
        atomicAdd(&accum[128 + tid], accI[tid]);
    }
    if (tid == 0) atomicAdd(&accum[0], loss_sh);
}

// ---------------- kernel 3: finalize scalars ----------------
__global__ __launch_bounds__(128) void k_final(const float* __restrict__ accum,
                                               float* __restrict__ out)
{
    __shared__ float s[128];
    int t = threadIdx.x;
    float term = 0.f;
    if (t < 127) {
        float a = accum[1 + t] / accum[128 + t];
        int depth = 32 - __clz(t + 1);                 // floor(log2(t+1)) + 1
        float lmbda = 0.1f * exp2f(-(float)depth);
        term = -lmbda * 0.5f * (logf(a) + log1pf(-a));
    }
    s[t] = term;
    __syncthreads();
    if (t == 0) {
        float c = 0.f;
        for (int i = 0; i < 127; ++i) c += s[i];
        out[819201] = c;                               // C
        out[0] = -accum[0] / 8192.0f;                  // neg_loss
    }
}

// ---------------- launcher ----------------
extern "C" void kernel_launch(void* const* d_in, const int* in_sizes, int n_in,
                              void* d_out, int out_size, void* d_ws, size_t ws_size,
                              hipStream_t stream)
{
    const float* x      = (const float*)d_in[0];
    const int*   labels = (const int*)  d_in[1];
    const float* W      = (const float*)d_in[2];
    const float* bias   = (const float*)d_in[3];
    const float* beta   = (const float*)d_in[4];
    const float* leaf   = (const float*)d_in[5];
    float* out = (float*)d_out;
    float* ws  = (float*)d_ws;

    float* accum = ws;                 // 256 floats
    float* logQT = ws + OFF_LOGQT;     // 100*256
    float* Q     = ws + OFF_Q;         // 256*100
    float* p     = ws + OFF_P;         // 8192*256

    hipMemsetAsync(accum, 0, 256 * sizeof(float), stream);
    k_logsoftmax<<<256, 64, 0, stream>>>(leaf, logQT, Q);
    k_gemm_sig<<<dim3(128, 4), 256, 0, stream>>>(x, W, bias, beta, p);
    k_tree<<<512, 256, 0, stream>>>(p, labels, logQT, Q, accum, out);
    k_final<<<1, 128, 0, stream>>>(accum, out);
}

// Round 6
// 201.594 us; speedup vs baseline: 1.5147x; 1.5147x over previous
//
#include <hip/hip_runtime.h>
#include <math.h>

typedef __attribute__((ext_vector_type(4)))  short short4v;
typedef __attribute__((ext_vector_type(8)))  short short8v;
typedef __attribute__((ext_vector_type(4)))  float f32x4;

// ---------------- ws layout (float units) ----------------
// accum  [0..255]      : [0]=loss, [1..127]=sum p*inner, [128..254]=sum inner
// logQT  [256..)       : [100][256]
// Q                     : [256][100]
// whi/wlo (ushort)      : [256][2048] bf16 hi / lo of W (row 255 zero)
// part0  (= p after sig): [8192][256] fp32
// part1                 : [8192][256] fp32 (only if ws_size permits)
#define OFF_LOGQT 256
#define OFF_Q     25856
#define OFF_WHI   51456
#define OFF_WLO   313600
#define OFF_P0    575744
#define OFF_P1    2672896

__device__ __forceinline__ unsigned short f2bf(float f) {   // RNE truncate to bf16 bits
    unsigned int b = __float_as_uint(f);
    unsigned int r = (b + 0x7FFFu + ((b >> 16) & 1u)) >> 16;
    return (unsigned short)r;
}
__device__ __forceinline__ float bf2f(unsigned short u) {
    return __uint_as_float(((unsigned int)u) << 16);
}

// ---------------- kernel: W -> bf16 hi/lo ----------------
__global__ __launch_bounds__(256) void k_wconv(const float* __restrict__ W,
                                               unsigned short* __restrict__ whi,
                                               unsigned short* __restrict__ wlo)
{
    int g = (blockIdx.x * 256 + threadIdx.x) * 8;      // 0..524280, covers 256*2048
    int row = g >> 11;
    unsigned short h[8], l[8];
    if (row < 255) {
        const float* src = W + (size_t)row * 2048 + (g & 2047);
        float4 v0 = *(const float4*)src;
        float4 v1 = *(const float4*)(src + 4);
        float vv[8] = {v0.x, v0.y, v0.z, v0.w, v1.x, v1.y, v1.z, v1.w};
#pragma unroll
        for (int j = 0; j < 8; ++j) {
            h[j] = f2bf(vv[j]);
            l[j] = f2bf(vv[j] - bf2f(h[j]));
        }
    } else {
#pragma unroll
        for (int j = 0; j < 8; ++j) { h[j] = 0; l[j] = 0; }
    }
#pragma unroll
    for (int j = 0; j < 8; ++j) { whi[g + j] = h[j]; wlo[g + j] = l[j]; }
}

// ---------------- kernel: log_softmax of leaf_params ----------------
__global__ __launch_bounds__(64) void k_logsoftmax(const float* __restrict__ lp,
                                                   float* __restrict__ logQT,
                                                   float* __restrict__ Q)
{
    int r = blockIdx.x;           // leaf 0..255
    int lane = threadIdx.x;       // 0..63
    float v0 = (lane < 100)      ? lp[r * 100 + lane]      : -INFINITY;
    float v1 = (lane + 64 < 100) ? lp[r * 100 + lane + 64] : -INFINITY;
    float m = fmaxf(v0, v1);
    for (int s = 32; s; s >>= 1) m = fmaxf(m, __shfl_xor(m, s));
    float e = 0.f;
    if (lane < 100)      e += expf(v0 - m);
    if (lane + 64 < 100) e += expf(v1 - m);
    for (int s = 32; s; s >>= 1) e += __shfl_xor(e, s);
    float logZ = m + logf(e);
    if (lane < 100) {
        float lq = v0 - logZ;
        Q[r * 100 + lane] = expf(lq);
        logQT[lane * 256 + r] = lq;
    }
    if (lane + 64 < 100) {
        float lq = v1 - logZ;
        Q[r * 100 + lane + 64] = expf(lq);
        logQT[(lane + 64) * 256 + r] = lq;
    }
}

// ---------------- kernel: split-bf16 MFMA GEMM ----------------
// C[i][n] = sum_k x[i][k]*W[n][k]; acc = xh*Wh + xh*Wl + xl*Wh (fp32 acc)
// BM=BN=128, BK=64, 256 threads (4 waves, wave-tile 64x64).
// grid (64, 2, KSPLIT): x = M-tile, y = N-tile, z = K-split. Writes fp32 partials.
#define GBK 64
#define LDR 136         // LDS row stride in shorts: [0..63]=hi, [64..127]=lo, +8 pad

__global__ __launch_bounds__(256, 1) void k_gemm(const float* __restrict__ x,
                                                 const unsigned short* __restrict__ whi,
                                                 const unsigned short* __restrict__ wlo,
                                                 float* __restrict__ part,
                                                 int ksteps)   // K-steps per WG
{
    __shared__ unsigned short As[128 * LDR];
    __shared__ unsigned short Bs[128 * LDR];

    const int tid  = threadIdx.x;
    const int w    = tid >> 6, lane = tid & 63;
    const int wm   = w >> 1, wn = w & 1;
    const int r16  = lane & 15, hi8 = (lane >> 4) * 8;
    const int row0 = blockIdx.x * 128;
    const int col0 = blockIdx.y * 128;
    const int kz   = blockIdx.z;
    const size_t kbase = (size_t)kz * ksteps * GBK;
    float* pdst = part + (size_t)kz * (8192 * 256);

    f32x4 acc[4][4] = {};

    float4  aR[8];
    short8v bH[4], bL[4];

    auto GL = [&](int s) {
        const size_t k0 = kbase + (size_t)s * GBK;
#pragma unroll
        for (int i = 0; i < 8; ++i) {
            int g = tid + i * 256;
            int ar = g >> 4, ac = (g & 15) * 4;
            aR[i] = *(const float4*)(x + (size_t)(row0 + ar) * 2048 + k0 + ac);
        }
#pragma unroll
        for (int i = 0; i < 4; ++i) {
            int g = tid + i * 256;
            int br = g >> 3, bc = (g & 7) * 8;
            size_t wo = (size_t)(col0 + br) * 2048 + k0 + bc;
            bH[i] = *(const short8v*)(whi + wo);
            bL[i] = *(const short8v*)(wlo + wo);
        }
    };

    auto DSW = [&]() {
#pragma unroll
        for (int i = 0; i < 8; ++i) {
            int g = tid + i * 256;
            int ar = g >> 4, ac = (g & 15) * 4;
            float vv[4] = {aR[i].x, aR[i].y, aR[i].z, aR[i].w};
            short4v hv, lv;
#pragma unroll
            for (int j = 0; j < 4; ++j) {
                unsigned short hb = f2bf(vv[j]);
                hv[j] = (short)hb;
                lv[j] = (short)f2bf(vv[j] - bf2f(hb));
            }
            *(short4v*)&As[ar * LDR + ac]      = hv;
            *(short4v*)&As[ar * LDR + 64 + ac] = lv;
        }
#pragma unroll
        for (int i = 0; i < 4; ++i) {
            int g = tid + i * 256;
            int br = g >> 3, bc = (g & 7) * 8;
            *(short8v*)&Bs[br * LDR + bc]      = bH[i];
            *(short8v*)&Bs[br * LDR + 64 + bc] = bL[i];
        }
    };

    GL(0);
    for (int s = 0; s < ksteps; ++s) {
        DSW();
        __syncthreads();
        if (s + 1 < ksteps) GL(s + 1);
#pragma unroll
        for (int kk = 0; kk < 2; ++kk) {
            const int kc = kk * 32 + hi8;
            short8v ah[4], al[4];
#pragma unroll
            for (int fm = 0; fm < 4; ++fm) {
                int base = (wm * 64 + fm * 16 + r16) * LDR + kc;
                ah[fm] = *(const short8v*)&As[base];
                al[fm] = *(const short8v*)&As[base + 64];
            }
#pragma unroll
            for (int fn = 0; fn < 4; ++fn) {
                int bb = (wn * 64 + fn * 16 + r16) * LDR + kc;
                short8v bhh = *(const short8v*)&Bs[bb];
                short8v bll = *(const short8v*)&Bs[bb + 64];
#pragma unroll
                for (int fm = 0; fm < 4; ++fm) {
                    acc[fm][fn] = __builtin_amdgcn_mfma_f32_16x16x32_bf16(ah[fm], bhh, acc[fm][fn], 0, 0, 0);
                    acc[fm][fn] = __builtin_amdgcn_mfma_f32_16x16x32_bf16(ah[fm], bll, acc[fm][fn], 0, 0, 0);
                    acc[fm][fn] = __builtin_amdgcn_mfma_f32_16x16x32_bf16(al[fm], bhh, acc[fm][fn], 0, 0, 0);
                }
            }
        }
        __syncthreads();
    }

    // epilogue: D[row][col], row = (lane>>4)*4 + j, col = lane&15
#pragma unroll
    for (int fm = 0; fm < 4; ++fm) {
#pragma unroll
        for (int fn = 0; fn < 4; ++fn) {
            int col = col0 + wn * 64 + fn * 16 + r16;
#pragma unroll
            for (int j = 0; j < 4; ++j) {
                int row = row0 + wm * 64 + fm * 16 + (lane >> 4) * 4 + j;
                pdst[(size_t)row * 256 + col] = acc[fm][fn][j];
            }
        }
    }
}

// ---------------- kernel: combine partials + bias + beta + sigmoid ----------------
__global__ __launch_bounds__(256) void k_sig(float* __restrict__ p0,
                                             const float* __restrict__ p1,
                                             const float* __restrict__ bias,
                                             const float* __restrict__ beta,
                                             int use2)
{
    int idx = blockIdx.x * 256 + threadIdx.x;          // float4 index over 8192*256
    float4 a = ((const float4*)p0)[idx];
    float4 b = use2 ? ((const float4*)p1)[idx] : make_float4(0.f, 0.f, 0.f, 0.f);
    int c0 = (idx & 63) * 4;
    float av[4] = {a.x, a.y, a.z, a.w};
    float bv[4] = {b.x, b.y, b.z, b.w};
    float r[4];
#pragma unroll
    for (int j = 0; j < 4; ++j) {
        int c = c0 + j; if (c > 254) c = 254;          // col 255 never read downstream
        float t = beta[c] * (av[j] + bv[j] + bias[c]);
        r[j] = 1.f / (1.f + expf(-t));
    }
    ((float4*)p0)[idx] = make_float4(r[0], r[1], r[2], r[3]);
}

// ---------------- kernel: tree pass ----------------
// 1024 blocks x 256 thr; 4 waves/block, 2 rows per wave, wave-local sync only.
__global__ __launch_bounds__(256) void k_tree(const float* __restrict__ p,
                                              const int* __restrict__ labels,
                                              const float* __restrict__ logQT,
                                              const float* __restrict__ Q,
                                              float* __restrict__ accum,
                                              float* __restrict__ out)
{
    __shared__ float psh[4][256];
    __shared__ float accPI[127];
    __shared__ float accI[127];
    __shared__ float loss_sh;
    int tid = threadIdx.x;
    int w = tid >> 6, lane = tid & 63;
    if (tid < 127) { accPI[tid] = 0.f; accI[tid] = 0.f; }
    if (tid == 255) loss_sh = 0.f;
    __syncthreads();

    for (int rr = 0; rr < 2; ++rr) {
        int b = blockIdx.x * 8 + w * 2 + rr;
        *(float4*)&psh[w][lane * 4] = *(const float4*)&p[(size_t)b * 256 + lane * 4];
        asm volatile("s_waitcnt lgkmcnt(0)" ::: "memory");   // wave-local: writes visible
        __builtin_amdgcn_sched_barrier(0);

        int label = labels[b];
        float4 tq = *(const float4*)&logQT[(size_t)label * 256 + lane * 4];

        // leaf paths for leaves lane*4 + {0,1,2,3}: shared prefix depths 0..5
        float prefix = 1.f;
#pragma unroll
        for (int d = 0; d < 6; ++d) {
            int node = (1 << d) - 1 + (lane >> (6 - d));
            float g = psh[w][node];
            prefix *= ((lane >> (5 - d)) & 1) ? g : (1.f - g);
        }
        float g6  = psh[w][63 + lane];
        float p60 = prefix * (1.f - g6), p61 = prefix * g6;
        float g7a = psh[w][127 + 2 * lane];
        float g7b = psh[w][128 + 2 * lane];
        float f0 = p60 * (1.f - g7a), f1 = p60 * g7a;
        float f2 = p61 * (1.f - g7b), f3 = p61 * g7b;

        float lsum = f0 * tq.x + f1 * tq.y + f2 * tq.z + f3 * tq.w;

        float best = f0; int bestIdx = lane * 4;
        if (f1 > best) { best = f1; bestIdx = lane * 4 + 1; }
        if (f2 > best) { best = f2; bestIdx = lane * 4 + 2; }
        if (f3 > best) { best = f3; bestIdx = lane * 4 + 3; }

        for (int s = 32; s; s >>= 1) lsum += __shfl_xor(lsum, s);
        for (int s = 32; s; s >>= 1) {
            float ov = __shfl_xor(best, s);
            int   oi = __shfl_xor(bestIdx, s);
            if (ov > best || (ov == best && oi < bestIdx)) { best = ov; bestIdx = oi; }
        }
        if (lane == 0) atomicAdd(&loss_sh, lsum);

        // inner-path sums for nodes 0..126
#pragma unroll
        for (int t = 0; t < 2; ++t) {
            int n = lane + t * 64;
            if (n < 127) {
                float f = 1.f;
                int cur = n;
                while (cur > 0) {
                    int par = (cur - 1) >> 1;
                    float g = psh[w][par];
                    f *= (cur == 2 * par + 2) ? g : (1.f - g);
                    cur = par;
                }
                atomicAdd(&accPI[n], psh[w][n] * f);
                atomicAdd(&accI[n], f);
            }
        }

        // output row = Q[best leaf]
        const float* qrow = Q + (size_t)bestIdx * 100;
        float* orow = out + 1 + (size_t)b * 100;
        orow[lane] = qrow[lane];
        if (lane < 36) orow[64 + lane] = qrow[64 + lane];
    }

    __syncthreads();
    if (tid < 127) {
        atomicAdd(&accum[1 + tid],   accPI[tid]);
        atomicAdd(&accum[128 + tid], accI[tid]);
    }
    if (tid == 0) atomicAdd(&accum[0], loss_sh);
}

// ---------------- kernel: finalize scalars ----------------
__global__ __launch_bounds__(128) void k_final(const float* __restrict__ accum,
                                               float* __restrict__ out)
{
    __shared__ float s[128];
    int t = threadIdx.x;
    float term = 0.f;
    if (t < 127) {
        float a = accum[1 + t] / accum[128 + t];
        int depth = 32 - __clz(t + 1);                 // floor(log2(t+1)) + 1
        float lmbda = 0.1f * exp2f(-(float)depth);
        term = -lmbda * 0.5f * (logf(a) + log1pf(-a));
    }
    s[t] = term;
    __syncthreads();
    if (t == 0) {
        float c = 0.f;
        for (int i = 0; i < 127; ++i) c += s[i];
        out[819201] = c;                               // C
        out[0] = -accum[0] / 8192.0f;                  // neg_loss
    }
}

// ---------------- launcher ----------------
extern "C" void kernel_launch(void* const* d_in, const int* in_sizes, int n_in,
                              void* d_out, int out_size, void* d_ws, size_t ws_size,
                              hipStream_t stream)
{
    const float* x      = (const float*)d_in[0];
    const int*   labels = (const int*)  d_in[1];
    const float* W      = (const float*)d_in[2];
    const float* bias   = (const float*)d_in[3];
    const float* beta   = (const float*)d_in[4];
    const float* leaf   = (const float*)d_in[5];
    float* out = (float*)d_out;
    float* ws  = (float*)d_ws;

    float*          accum = ws;
    float*          logQT = ws + OFF_LOGQT;
    float*          Q     = ws + OFF_Q;
    unsigned short* whi   = (unsigned short*)(ws + OFF_WHI);
    unsigned short* wlo   = (unsigned short*)(ws + OFF_WLO);
    float*          part0 = ws + OFF_P0;    // becomes p after k_sig
    float*          part1 = ws + OFF_P1;

    // K-split 2 needs ws through OFF_P1 + 8192*256 floats (~19.1 MB)
    const size_t need2 = (size_t)(OFF_P1 + 8192 * 256) * sizeof(float);
    const int use2 = (ws_size >= need2) ? 1 : 0;
    const int ksteps = use2 ? 16 : 32;     // 2048 / (GBK * KSPLIT)

    hipMemsetAsync(accum, 0, 256 * sizeof(float), stream);
    k_wconv<<<256, 256, 0, stream>>>(W, whi, wlo);
    k_logsoftmax<<<256, 64, 0, stream>>>(leaf, logQT, Q);
    k_gemm<<<dim3(64, 2, use2 ? 2 : 1), 256, 0, stream>>>(x, whi, wlo, part0, ksteps);
    k_sig<<<2048, 256, 0, stream>>>(part0, part1, bias, beta, use2);
    k_tree<<<1024, 256, 0, stream>>>(part0, labels, logQT, Q, accum, out);
    k_final<<<1, 128, 0, stream>>>(accum, out);
}

// Round 7
// 193.994 us; speedup vs baseline: 1.5741x; 1.0392x over previous
//
#include <hip/hip_runtime.h>
#include <math.h>

typedef __attribute__((ext_vector_type(4)))  short short4v;
typedef __attribute__((ext_vector_type(8)))  short short8v;
typedef __attribute__((ext_vector_type(4)))  float f32x4;

// ---------------- ws layout (float units) ----------------
// accum  [0..255]      : [0]=loss, [1..127]=sum p*inner, [128..254]=sum inner
// logQT                 : [100][256]
// Q                     : [256][100]
// whi/wlo (ushort)      : [256][2048] bf16 hi / lo of W (row 255 zero)
// part[z]               : [8192][256] fp32 GEMM partials, z < KSPLIT
#define OFF_LOGQT 256
#define OFF_Q     25856
#define OFF_WHI   51456
#define OFF_WLO   313600
#define OFF_P0    575744
#define PART_STRIDE 2097152   // 8192*256 floats

__device__ __forceinline__ unsigned short f2bf(float f) {   // RNE to bf16 bits
    unsigned int b = __float_as_uint(f);
    unsigned int r = (b + 0x7FFFu + ((b >> 16) & 1u)) >> 16;
    return (unsigned short)r;
}
__device__ __forceinline__ float bf2f(unsigned short u) {
    return __uint_as_float(((unsigned int)u) << 16);
}

// ---------------- kernel: prep = W->hi/lo  +  log_softmax  +  accum zero ----------------
// blocks 0..255: W conversion (+ block 0 zeroes accum); blocks 256..319: log_softmax (4 leaves/block)
__global__ __launch_bounds__(256) void k_prep(const float* __restrict__ W,
                                              unsigned short* __restrict__ whi,
                                              unsigned short* __restrict__ wlo,
                                              const float* __restrict__ lp,
                                              float* __restrict__ logQT,
                                              float* __restrict__ Q,
                                              float* __restrict__ accum)
{
    const int bx = blockIdx.x, tid = threadIdx.x;
    if (bx < 256) {
        if (bx == 0) accum[tid] = 0.f;
        int g = (bx * 256 + tid) * 8;
        int row = g >> 11;
        unsigned short h[8], l[8];
        if (row < 255) {
            const float* src = W + (size_t)row * 2048 + (g & 2047);
            float4 v0 = *(const float4*)src;
            float4 v1 = *(const float4*)(src + 4);
            float vv[8] = {v0.x, v0.y, v0.z, v0.w, v1.x, v1.y, v1.z, v1.w};
#pragma unroll
            for (int j = 0; j < 8; ++j) {
                h[j] = f2bf(vv[j]);
                l[j] = f2bf(vv[j] - bf2f(h[j]));
            }
        } else {
#pragma unroll
            for (int j = 0; j < 8; ++j) { h[j] = 0; l[j] = 0; }
        }
#pragma unroll
        for (int j = 0; j < 8; ++j) { whi[g + j] = h[j]; wlo[g + j] = l[j]; }
    } else {
        int w = tid >> 6, lane = tid & 63;
        int r = (bx - 256) * 4 + w;                  // leaf 0..255
        float v0 = (lane < 100)      ? lp[r * 100 + lane]      : -INFINITY;
        float v1 = (lane + 64 < 100) ? lp[r * 100 + lane + 64] : -INFINITY;
        float m = fmaxf(v0, v1);
        for (int s = 32; s; s >>= 1) m = fmaxf(m, __shfl_xor(m, s));
        float e = 0.f;
        if (lane < 100)      e += expf(v0 - m);
        if (lane + 64 < 100) e += expf(v1 - m);
        for (int s = 32; s; s >>= 1) e += __shfl_xor(e, s);
        float logZ = m + logf(e);
        if (lane < 100) {
            float lq = v0 - logZ;
            Q[r * 100 + lane] = expf(lq);
            logQT[lane * 256 + r] = lq;
        }
        if (lane + 64 < 100) {
            float lq = v1 - logZ;
            Q[r * 100 + lane + 64] = expf(lq);
            logQT[(lane + 64) * 256 + r] = lq;
        }
    }
}

// ---------------- kernel: split-bf16 MFMA GEMM ----------------
// C[i][n] = sum_k x[i][k]*W[n][k]; acc = xh*Wh + xh*Wl + xl*Wh (fp32 acc)
// BM=BN=128, BK=64, 256 threads (4 waves, wave-tile 64x64).
// grid (64, 2, KSPLIT). Writes fp32 partials per K-split.
#define GBK 64
#define LDR 136         // LDS row stride in shorts: [0..63]=hi, [64..127]=lo, +8 pad

__global__ __launch_bounds__(256, 1) void k_gemm(const float* __restrict__ x,
                                                 const unsigned short* __restrict__ whi,
                                                 const unsigned short* __restrict__ wlo,
                                                 float* __restrict__ part,
                                                 int ksteps)
{
    __shared__ unsigned short As[128 * LDR];
    __shared__ unsigned short Bs[128 * LDR];

    const int tid  = threadIdx.x;
    const int w    = tid >> 6, lane = tid & 63;
    const int wm   = w >> 1, wn = w & 1;
    const int r16  = lane & 15, hi8 = (lane >> 4) * 8;
    const int row0 = blockIdx.x * 128;
    const int col0 = blockIdx.y * 128;
    const int kz   = blockIdx.z;
    const size_t kbase = (size_t)kz * ksteps * GBK;
    float* pdst = part + (size_t)kz * PART_STRIDE;

    f32x4 acc[4][4] = {};

    float4  aR[8];
    short8v bH[4], bL[4];

    auto GL = [&](int s) {
        const size_t k0 = kbase + (size_t)s * GBK;
#pragma unroll
        for (int i = 0; i < 8; ++i) {
            int g = tid + i * 256;
            int ar = g >> 4, ac = (g & 15) * 4;
            aR[i] = *(const float4*)(x + (size_t)(row0 + ar) * 2048 + k0 + ac);
        }
#pragma unroll
        for (int i = 0; i < 4; ++i) {
            int g = tid + i * 256;
            int br = g >> 3, bc = (g & 7) * 8;
            size_t wo = (size_t)(col0 + br) * 2048 + k0 + bc;
            bH[i] = *(const short8v*)(whi + wo);
            bL[i] = *(const short8v*)(wlo + wo);
        }
    };

    auto DSW = [&]() {
#pragma unroll
        for (int i = 0; i < 8; ++i) {
            int g = tid + i * 256;
            int ar = g >> 4, ac = (g & 15) * 4;
            float vv[4] = {aR[i].x, aR[i].y, aR[i].z, aR[i].w};
            short4v hv, lv;
#pragma unroll
            for (int j = 0; j < 4; ++j) {
                unsigned short hb = f2bf(vv[j]);
                hv[j] = (short)hb;
                lv[j] = (short)f2bf(vv[j] - bf2f(hb));
            }
            *(short4v*)&As[ar * LDR + ac]      = hv;
            *(short4v*)&As[ar * LDR + 64 + ac] = lv;
        }
#pragma unroll
        for (int i = 0; i < 4; ++i) {
            int g = tid + i * 256;
            int br = g >> 3, bc = (g & 7) * 8;
            *(short8v*)&Bs[br * LDR + bc]      = bH[i];
            *(short8v*)&Bs[br * LDR + 64 + bc] = bL[i];
        }
    };

    GL(0);
    for (int s = 0; s < ksteps; ++s) {
        DSW();
        __syncthreads();
        if (s + 1 < ksteps) GL(s + 1);
#pragma unroll
        for (int kk = 0; kk < 2; ++kk) {
            const int kc = kk * 32 + hi8;
            short8v ah[4], al[4];
#pragma unroll
            for (int fm = 0; fm < 4; ++fm) {
                int base = (wm * 64 + fm * 16 + r16) * LDR + kc;
                ah[fm] = *(const short8v*)&As[base];
                al[fm] = *(const short8v*)&As[base + 64];
            }
#pragma unroll
            for (int fn = 0; fn < 4; ++fn) {
                int bb = (wn * 64 + fn * 16 + r16) * LDR + kc;
                short8v bhh = *(const short8v*)&Bs[bb];
                short8v bll = *(const short8v*)&Bs[bb + 64];
#pragma unroll
                for (int fm = 0; fm < 4; ++fm) {
                    acc[fm][fn] = __builtin_amdgcn_mfma_f32_16x16x32_bf16(ah[fm], bhh, acc[fm][fn], 0, 0, 0);
                    acc[fm][fn] = __builtin_amdgcn_mfma_f32_16x16x32_bf16(ah[fm], bll, acc[fm][fn], 0, 0, 0);
                    acc[fm][fn] = __builtin_amdgcn_mfma_f32_16x16x32_bf16(al[fm], bhh, acc[fm][fn], 0, 0, 0);
                }
            }
        }
        __syncthreads();
    }

#pragma unroll
    for (int fm = 0; fm < 4; ++fm) {
#pragma unroll
        for (int fn = 0; fn < 4; ++fn) {
            int col = col0 + wn * 64 + fn * 16 + r16;
#pragma unroll
            for (int j = 0; j < 4; ++j) {
                int row = row0 + wm * 64 + fm * 16 + (lane >> 4) * 4 + j;
                pdst[(size_t)row * 256 + col] = acc[fm][fn][j];
            }
        }
    }
}

// ---------------- kernel: fused sigmoid + tree pass ----------------
// 1024 blocks x 256 thr; 4 waves/block, 2 rows/wave, wave-local sync; register accumulators.
__global__ __launch_bounds__(256) void k_tree(const float* __restrict__ part, int npart,
                                              const float* __restrict__ bias,
                                              const float* __restrict__ beta,
                                              const int* __restrict__ labels,
                                              const float* __restrict__ logQT,
                                              const float* __restrict__ Q,
                                              float* __restrict__ accum,
                                              float* __restrict__ out)
{
    __shared__ float psh[4][256];
    __shared__ float redPI[4][128];
    __shared__ float redI[4][128];
    __shared__ float lossw[4];
    const int tid = threadIdx.x;
    const int w = tid >> 6, lane = tid & 63;
    const int c0 = lane * 4;

    float4 bi, be;
    if (lane < 63) {
        bi = *(const float4*)&bias[c0];
        be = *(const float4*)&beta[c0];
    } else {
        bi = make_float4(bias[252], bias[253], bias[254], 0.f);
        be = make_float4(beta[252], beta[253], beta[254], 0.f);
    }

    float aPI0 = 0.f, aPI1 = 0.f, aI0 = 0.f, aI1 = 0.f, lossAcc = 0.f;

    for (int rr = 0; rr < 2; ++rr) {
        int b = blockIdx.x * 8 + w * 2 + rr;

        // gather partials, combine, sigmoid
        float4 s = make_float4(0.f, 0.f, 0.f, 0.f);
        for (int z = 0; z < npart; ++z) {
            float4 v = *(const float4*)&part[(size_t)z * PART_STRIDE + (size_t)b * 256 + c0];
            s.x += v.x; s.y += v.y; s.z += v.z; s.w += v.w;
        }
        float4 pv;
        pv.x = 1.f / (1.f + expf(-be.x * (s.x + bi.x)));
        pv.y = 1.f / (1.f + expf(-be.y * (s.y + bi.y)));
        pv.z = 1.f / (1.f + expf(-be.z * (s.z + bi.z)));
        pv.w = 1.f / (1.f + expf(-be.w * (s.w + bi.w)));
        *(float4*)&psh[w][c0] = pv;
        asm volatile("s_waitcnt lgkmcnt(0)" ::: "memory");   // wave-local visibility
        __builtin_amdgcn_sched_barrier(0);

        int label = labels[b];
        float4 tq = *(const float4*)&logQT[(size_t)label * 256 + c0];

        // leaf paths for leaves lane*4 + {0..3}: shared prefix depths 0..5
        float prefix = 1.f;
#pragma unroll
        for (int d = 0; d < 6; ++d) {
            int node = (1 << d) - 1 + (lane >> (6 - d));
            float g = psh[w][node];
            prefix *= ((lane >> (5 - d)) & 1) ? g : (1.f - g);
        }
        float g6  = psh[w][63 + lane];
        float p60 = prefix * (1.f - g6), p61 = prefix * g6;
        float g7a = psh[w][127 + 2 * lane];
        float g7b = psh[w][128 + 2 * lane];
        float f0 = p60 * (1.f - g7a), f1 = p60 * g7a;
        float f2 = p61 * (1.f - g7b), f3 = p61 * g7b;

        float lsum = f0 * tq.x + f1 * tq.y + f2 * tq.z + f3 * tq.w;

        float best = f0; int bestIdx = c0;
        if (f1 > best) { best = f1; bestIdx = c0 + 1; }
        if (f2 > best) { best = f2; bestIdx = c0 + 2; }
        if (f3 > best) { best = f3; bestIdx = c0 + 3; }

        for (int sft = 32; sft; sft >>= 1) lsum += __shfl_xor(lsum, sft);
        for (int sft = 32; sft; sft >>= 1) {
            float ov = __shfl_xor(best, sft);
            int   oi = __shfl_xor(bestIdx, sft);
            if (ov > best || (ov == best && oi < bestIdx)) { best = ov; bestIdx = oi; }
        }
        lossAcc += lsum;   // identical on all lanes; lane 0's used at end

        // inner-path products for nodes n=lane and n=lane+64 (register accumulate)
        {
            int n = lane;
            float f = 1.f;
            int cur = n;
            while (cur > 0) {
                int par = (cur - 1) >> 1;
                float g = psh[w][par];
                f *= (cur == 2 * par + 2) ? g : (1.f - g);
                cur = par;
            }
            aPI0 += psh[w][n] * f;
            aI0  += f;
        }
        if (lane < 63) {
            int n = lane + 64;
            float f = 1.f;
            int cur = n;
            while (cur > 0) {
                int par = (cur - 1) >> 1;
                float g = psh[w][par];
                f *= (cur == 2 * par + 2) ? g : (1.f - g);
                cur = par;
            }
            aPI1 += psh[w][n] * f;
            aI1  += f;
        }

        // output row = Q[best leaf]
        const float* qrow = Q + (size_t)bestIdx * 100;
        float* orow = out + 1 + (size_t)b * 100;
        orow[lane] = qrow[lane];
        if (lane < 36) orow[64 + lane] = qrow[64 + lane];
    }

    // block-level reduction, then global atomics (once per block)
    redPI[w][lane] = aPI0;           redI[w][lane] = aI0;
    redPI[w][64 + lane] = (lane < 63) ? aPI1 : 0.f;
    redI [w][64 + lane] = (lane < 63) ? aI1  : 0.f;
    if (lane == 0) lossw[w] = lossAcc;
    __syncthreads();
    if (tid < 127) {
        float sPI = redPI[0][tid] + redPI[1][tid] + redPI[2][tid] + redPI[3][tid];
        float sI  = redI [0][tid] + redI [1][tid] + redI [2][tid] + redI [3][tid];
        atomicAdd(&accum[1 + tid],   sPI);
        atomicAdd(&accum[128 + tid], sI);
    }
    if (tid == 128) {
        atomicAdd(&accum[0], lossw[0] + lossw[1] + lossw[2] + lossw[3]);
    }
}

// ---------------- kernel: finalize scalars ----------------
__global__ __launch_bounds__(128) void k_final(const float* __restrict__ accum,
                                               float* __restrict__ out)
{
    __shared__ float s[128];
    int t = threadIdx.x;
    float term = 0.f;
    if (t < 127) {
        float a = accum[1 + t] / accum[128 + t];
        int depth = 32 - __clz(t + 1);                 // floor(log2(t+1)) + 1
        float lmbda = 0.1f * exp2f(-(float)depth);
        term = -lmbda * 0.5f * (logf(a) + log1pf(-a));
    }
    s[t] = term;
    __syncthreads();
    if (t == 0) {
        float c = 0.f;
        for (int i = 0; i < 127; ++i) c += s[i];
        out[819201] = c;                               // C
        out[0] = -accum[0] / 8192.0f;                  // neg_loss
    }
}

// ---------------- launcher ----------------
extern "C" void kernel_launch(void* const* d_in, const int* in_sizes, int n_in,
                              void* d_out, int out_size, void* d_ws, size_t ws_size,
                              hipStream_t stream)
{
    const float* x      = (const float*)d_in[0];
    const int*   labels = (const int*)  d_in[1];
    const float* W      = (const float*)d_in[2];
    const float* bias   = (const float*)d_in[3];
    const float* beta   = (const float*)d_in[4];
    const float* leaf   = (const float*)d_in[5];
    float* out = (float*)d_out;
    float* ws  = (float*)d_ws;

    float*          accum = ws;
    float*          logQT = ws + OFF_LOGQT;
    float*          Q     = ws + OFF_Q;
    unsigned short* whi   = (unsigned short*)(ws + OFF_WHI);
    unsigned short* wlo   = (unsigned short*)(ws + OFF_WLO);
    float*          part  = ws + OFF_P0;

    auto need = [](int k) {
        return (size_t)(OFF_P0 + (size_t)k * PART_STRIDE) * sizeof(float);
    };
    int ksplit = (ws_size >= need(4)) ? 4 : (ws_size >= need(2)) ? 2 : 1;
    int ksteps = 32 / ksplit;          // 2048 / (GBK * ksplit)

    k_prep<<<320, 256, 0, stream>>>(W, whi, wlo, leaf, logQT, Q, accum);
    k_gemm<<<dim3(64, 2, ksplit), 256, 0, stream>>>(x, whi, wlo, part, ksteps);
    k_tree<<<1024, 256, 0, stream>>>(part, ksplit, bias, beta, labels, logQT, Q, accum, out);
    k_final<<<1, 128, 0, stream>>>(accum, out);
}

// Round 8
// 178.751 us; speedup vs baseline: 1.7083x; 1.0853x over previous
//
#include <hip/hip_runtime.h>
#include <math.h>

typedef __attribute__((ext_vector_type(4)))  short short4v;
typedef __attribute__((ext_vector_type(8)))  short short8v;
typedef __attribute__((ext_vector_type(4)))  float f32x4;

// ---------------- ws layout (float units) ----------------
// accum[0..255]: [0]=loss, [1..127]=sum p*inner, [128..254]=sum inner
#define OFF_LOGQT 256
#define OFF_Q     25856
#define OFF_WHI   51456
#define OFF_WLO   313600
#define OFF_XHI   575744            // new path: x hi bf16 [8192][2048]
#define OFF_XLO   8964352           // new path: x lo bf16
#define OFF_PART_NEW 17352960       // new path partials
#define OFF_PART_OLD 575744         // old path partials (xhl absent)
#define PART_STRIDE 2097152         // 8192*256 floats

__device__ __forceinline__ unsigned short f2bf(float f) {   // RNE to bf16 bits
    unsigned int b = __float_as_uint(f);
    unsigned int r = (b + 0x7FFFu + ((b >> 16) & 1u)) >> 16;
    return (unsigned short)r;
}
__device__ __forceinline__ float bf2f(unsigned short u) {
    return __uint_as_float(((unsigned int)u) << 16);
}
__device__ __forceinline__ void gl16(const void* g, void* l) {
    __builtin_amdgcn_global_load_lds(
        (const __attribute__((address_space(1))) unsigned int*)g,
        (__attribute__((address_space(3))) unsigned int*)l, 16, 0, 0);
}

// ---------------- kernel: prep = x->hl (optional) + W->hl + log_softmax + zero ----------------
__global__ __launch_bounds__(256) void k_prep(const float* __restrict__ x,
                                              unsigned short* __restrict__ xhi,
                                              unsigned short* __restrict__ xlo,
                                              int nxblk,
                                              const float* __restrict__ W,
                                              unsigned short* __restrict__ whi,
                                              unsigned short* __restrict__ wlo,
                                              const float* __restrict__ lp,
                                              float* __restrict__ logQT,
                                              float* __restrict__ Q,
                                              float* __restrict__ accum)
{
    const int bx = blockIdx.x, tid = threadIdx.x;
    if (bx < nxblk) {                       // x conversion: 8 elems/thread
        int g = bx * 2048 + tid * 8;
        float4 v0 = *(const float4*)(x + g);
        float4 v1 = *(const float4*)(x + g + 4);
        float vv[8] = {v0.x, v0.y, v0.z, v0.w, v1.x, v1.y, v1.z, v1.w};
        short4v h0, h1, l0, l1;
#pragma unroll
        for (int j = 0; j < 4; ++j) {
            unsigned short hb = f2bf(vv[j]);
            h0[j] = (short)hb; l0[j] = (short)f2bf(vv[j] - bf2f(hb));
            unsigned short hb2 = f2bf(vv[j + 4]);
            h1[j] = (short)hb2; l1[j] = (short)f2bf(vv[j + 4] - bf2f(hb2));
        }
        *(short4v*)(xhi + g) = h0;  *(short4v*)(xhi + g + 4) = h1;
        *(short4v*)(xlo + g) = l0;  *(short4v*)(xlo + g + 4) = l1;
        return;
    }
    const int bxx = bx - nxblk;
    if (bxx < 256) {                        // W conversion
        if (bxx == 0) accum[tid] = 0.f;
        int g = (bxx * 256 + tid) * 8;
        int row = g >> 11;
        unsigned short h[8], l[8];
        if (row < 255) {
            const float* src = W + (size_t)row * 2048 + (g & 2047);
            float4 v0 = *(const float4*)src;
            float4 v1 = *(const float4*)(src + 4);
            float vv[8] = {v0.x, v0.y, v0.z, v0.w, v1.x, v1.y, v1.z, v1.w};
#pragma unroll
            for (int j = 0; j < 8; ++j) {
                h[j] = f2bf(vv[j]);
                l[j] = f2bf(vv[j] - bf2f(h[j]));
            }
        } else {
#pragma unroll
            for (int j = 0; j < 8; ++j) { h[j] = 0; l[j] = 0; }
        }
#pragma unroll
        for (int j = 0; j < 8; ++j) { whi[g + j] = h[j]; wlo[g + j] = l[j]; }
    } else {                                // log_softmax: 4 leaves/block
        int w = tid >> 6, lane = tid & 63;
        int r = (bxx - 256) * 4 + w;
        float v0 = (lane < 100)      ? lp[r * 100 + lane]      : -INFINITY;
        float v1 = (lane + 64 < 100) ? lp[r * 100 + lane + 64] : -INFINITY;
        float m = fmaxf(v0, v1);
        for (int s = 32; s; s >>= 1) m = fmaxf(m, __shfl_xor(m, s));
        float e = 0.f;
        if (lane < 100)      e += expf(v0 - m);
        if (lane + 64 < 100) e += expf(v1 - m);
        for (int s = 32; s; s >>= 1) e += __shfl_xor(e, s);
        float logZ = m + logf(e);
        if (lane < 100) {
            float lq = v0 - logZ;
            Q[r * 100 + lane] = expf(lq);
            logQT[lane * 256 + r] = lq;
        }
        if (lane + 64 < 100) {
            float lq = v1 - logZ;
            Q[r * 100 + lane + 64] = expf(lq);
            logQT[(lane + 64) * 256 + r] = lq;
        }
    }
}

// ---------------- kernel: pure-bf16 MFMA GEMM (new path) ----------------
// BM=64, BN=256, BK=64; 4 waves, wave-tile 64x64; LDS 80KB -> 2 blocks/CU.
// Staging = global_load_lds only. grid (128, 1, ksplit).
__global__ __launch_bounds__(256, 2) void k_gemm2(const unsigned short* __restrict__ xhi,
                                                  const unsigned short* __restrict__ xlo,
                                                  const unsigned short* __restrict__ whi,
                                                  const unsigned short* __restrict__ wlo,
                                                  float* __restrict__ part,
                                                  int ksteps)
{
    __shared__ __align__(16) unsigned short Ah[64 * 64];
    __shared__ __align__(16) unsigned short Al[64 * 64];
    __shared__ __align__(16) unsigned short Bh[256 * 64];
    __shared__ __align__(16) unsigned short Bl[256 * 64];

    const int tid = threadIdx.x;
    const int w = tid >> 6, lane = tid & 63;
    const int r16 = lane & 15, hb = lane >> 4;
    const int row0 = blockIdx.x * 64;
    const int kz = blockIdx.z;
    float* pdst = part + (size_t)kz * PART_STRIDE;

    f32x4 acc[4][4] = {};

    for (int s = 0; s < ksteps; ++s) {
        const int k0 = (kz * ksteps + s) * 64;
#pragma unroll
        for (int it = 0; it < 2; ++it) {        // A tiles: 64x64 hi+lo
            int ch = it * 256 + tid;
            int r = ch >> 3, c = (ch & 7) * 8;
            gl16(xhi + (size_t)(row0 + r) * 2048 + k0 + c, &Ah[ch * 8]);
            gl16(xlo + (size_t)(row0 + r) * 2048 + k0 + c, &Al[ch * 8]);
        }
#pragma unroll
        for (int it = 0; it < 8; ++it) {        // B tiles: 256x64 hi+lo
            int ch = it * 256 + tid;
            int r = ch >> 3, c = (ch & 7) * 8;
            gl16(whi + (size_t)r * 2048 + k0 + c, &Bh[ch * 8]);
            gl16(wlo + (size_t)r * 2048 + k0 + c, &Bl[ch * 8]);
        }
        __syncthreads();                        // drains vmcnt before LDS reads
#pragma unroll
        for (int kk = 0; kk < 2; ++kk) {
            const int kc = kk * 32 + hb * 8;
            short8v ah[4], al[4];
#pragma unroll
            for (int fm = 0; fm < 4; ++fm) {
                ah[fm] = *(const short8v*)&Ah[(fm * 16 + r16) * 64 + kc];
                al[fm] = *(const short8v*)&Al[(fm * 16 + r16) * 64 + kc];
            }
#pragma unroll
            for (int fn = 0; fn < 4; ++fn) {
                int br = w * 64 + fn * 16 + r16;
                short8v bhh = *(const short8v*)&Bh[br * 64 + kc];
                short8v bll = *(const short8v*)&Bl[br * 64 + kc];
#pragma unroll
                for (int fm = 0; fm < 4; ++fm) {
                    acc[fm][fn] = __builtin_amdgcn_mfma_f32_16x16x32_bf16(ah[fm], bhh, acc[fm][fn], 0, 0, 0);
                    acc[fm][fn] = __builtin_amdgcn_mfma_f32_16x16x32_bf16(ah[fm], bll, acc[fm][fn], 0, 0, 0);
                    acc[fm][fn] = __builtin_amdgcn_mfma_f32_16x16x32_bf16(al[fm], bhh, acc[fm][fn], 0, 0, 0);
                }
            }
        }
        __syncthreads();
    }

#pragma unroll
    for (int fm = 0; fm < 4; ++fm)
#pragma unroll
        for (int fn = 0; fn < 4; ++fn) {
            int col = w * 64 + fn * 16 + r16;
#pragma unroll
            for (int j = 0; j < 4; ++j) {
                int row = row0 + fm * 16 + hb * 4 + j;
                pdst[(size_t)row * 256 + col] = acc[fm][fn][j];
            }
        }
}

// ---------------- kernel: fallback GEMM (round-7, validated): in-loop x conversion ----------------
#define GBK 64
#define LDR 136
__global__ __launch_bounds__(256, 1) void k_gemm_fb(const float* __restrict__ x,
                                                    const unsigned short* __restrict__ whi,
                                                    const unsigned short* __restrict__ wlo,
                                                    float* __restrict__ part,
                                                    int ksteps)
{
    __shared__ unsigned short As[128 * LDR];
    __shared__ unsigned short Bs[128 * LDR];
    const int tid  = threadIdx.x;
    const int w    = tid >> 6, lane = tid & 63;
    const int wm   = w >> 1, wn = w & 1;
    const int r16  = lane & 15, hi8 = (lane >> 4) * 8;
    const int row0 = blockIdx.x * 128;
    const int col0 = blockIdx.y * 128;
    const int kz   = blockIdx.z;
    const size_t kbase = (size_t)kz * ksteps * GBK;
    float* pdst = part + (size_t)kz * PART_STRIDE;
    f32x4 acc[4][4] = {};
    float4  aR[8];
    short8v bH[4], bL[4];
    auto GL = [&](int s) {
        const size_t k0 = kbase + (size_t)s * GBK;
#pragma unroll
        for (int i = 0; i < 8; ++i) {
            int g = tid + i * 256;
            int ar = g >> 4, ac = (g & 15) * 4;
            aR[i] = *(const float4*)(x + (size_t)(row0 + ar) * 2048 + k0 + ac);
        }
#pragma unroll
        for (int i = 0; i < 4; ++i) {
            int g = tid + i * 256;
            int br = g >> 3, bc = (g & 7) * 8;
            size_t wo = (size_t)(col0 + br) * 2048 + k0 + bc;
            bH[i] = *(const short8v*)(whi + wo);
            bL[i] = *(const short8v*)(wlo + wo);
        }
    };
    auto DSW = [&]() {
#pragma unroll
        for (int i = 0; i < 8; ++i) {
            int g = tid + i * 256;
            int ar = g >> 4, ac = (g & 15) * 4;
            float vv[4] = {aR[i].x, aR[i].y, aR[i].z, aR[i].w};
            short4v hv, lv;
#pragma unroll
            for (int j = 0; j < 4; ++j) {
                unsigned short hbv = f2bf(vv[j]);
                hv[j] = (short)hbv;
                lv[j] = (short)f2bf(vv[j] - bf2f(hbv));
            }
            *(short4v*)&As[ar * LDR + ac]      = hv;
            *(short4v*)&As[ar * LDR + 64 + ac] = lv;
        }
#pragma unroll
        for (int i = 0; i < 4; ++i) {
            int g = tid + i * 256;
            int br = g >> 3, bc = (g & 7) * 8;
            *(short8v*)&Bs[br * LDR + bc]      = bH[i];
            *(short8v*)&Bs[br * LDR + 64 + bc] = bL[i];
        }
    };
    GL(0);
    for (int s = 0; s < ksteps; ++s) {
        DSW();
        __syncthreads();
        if (s + 1 < ksteps) GL(s + 1);
#pragma unroll
        for (int kk = 0; kk < 2; ++kk) {
            const int kc = kk * 32 + hi8;
            short8v ah[4], al[4];
#pragma unroll
            for (int fm = 0; fm < 4; ++fm) {
                int base = (wm * 64 + fm * 16 + r16) * LDR + kc;
                ah[fm] = *(const short8v*)&As[base];
                al[fm] = *(const short8v*)&As[base + 64];
            }
#pragma unroll
            for (int fn = 0; fn < 4; ++fn) {
                int bb = (wn * 64 + fn * 16 + r16) * LDR + kc;
                short8v bhh = *(const short8v*)&Bs[bb];
                short8v bll = *(const short8v*)&Bs[bb + 64];
#pragma unroll
                for (int fm = 0; fm < 4; ++fm) {
                    acc[fm][fn] = __builtin_amdgcn_mfma_f32_16x16x32_bf16(ah[fm], bhh, acc[fm][fn], 0, 0, 0);
                    acc[fm][fn] = __builtin_amdgcn_mfma_f32_16x16x32_bf16(ah[fm], bll, acc[fm][fn], 0, 0, 0);
                    acc[fm][fn] = __builtin_amdgcn_mfma_f32_16x16x32_bf16(al[fm], bhh, acc[fm][fn], 0, 0, 0);
                }
            }
        }
        __syncthreads();
    }
#pragma unroll
    for (int fm = 0; fm < 4; ++fm)
#pragma unroll
        for (int fn = 0; fn < 4; ++fn) {
            int col = col0 + wn * 64 + fn * 16 + r16;
#pragma unroll
            for (int j = 0; j < 4; ++j) {
                int row = row0 + wm * 64 + fm * 16 + (lane >> 4) * 4 + j;
                pdst[(size_t)row * 256 + col] = acc[fm][fn][j];
            }
        }
}

// ---------------- kernel: fused sigmoid + tree pass ----------------
// 512 blocks x 256 thr; 4 waves/block, 4 rows/wave, wave-local sync; register accumulators.
__global__ __launch_bounds__(256) void k_tree(const float* __restrict__ part, int npart,
                                              const float* __restrict__ bias,
                                              const float* __restrict__ beta,
                                              const int* __restrict__ labels,
                                              const float* __restrict__ logQT,
                                              const float* __restrict__ Q,
                                              float* __restrict__ accum,
                                              float* __restrict__ out)
{
    __shared__ float psh[4][256];
    __shared__ float redPI[4][128];
    __shared__ float redI[4][128];
    __shared__ float lossw[4];
    const int tid = threadIdx.x;
    const int w = tid >> 6, lane = tid & 63;
    const int c0 = lane * 4;

    float4 bi, be;
    if (lane < 63) {
        bi = *(const float4*)&bias[c0];
        be = *(const float4*)&beta[c0];
    } else {
        bi = make_float4(bias[252], bias[253], bias[254], 0.f);
        be = make_float4(beta[252], beta[253], beta[254], 0.f);
    }

    float aPI0 = 0.f, aPI1 = 0.f, aI0 = 0.f, aI1 = 0.f, lossAcc = 0.f;

    for (int rr = 0; rr < 4; ++rr) {
        int b = blockIdx.x * 16 + w * 4 + rr;

        float4 s = make_float4(0.f, 0.f, 0.f, 0.f);
        for (int z = 0; z < npart; ++z) {
            float4 v = *(const float4*)&part[(size_t)z * PART_STRIDE + (size_t)b * 256 + c0];
            s.x += v.x; s.y += v.y; s.z += v.z; s.w += v.w;
        }
        float4 pv;
        pv.x = 1.f / (1.f + expf(-be.x * (s.x + bi.x)));
        pv.y = 1.f / (1.f + expf(-be.y * (s.y + bi.y)));
        pv.z = 1.f / (1.f + expf(-be.z * (s.z + bi.z)));
        pv.w = 1.f / (1.f + expf(-be.w * (s.w + bi.w)));
        *(float4*)&psh[w][c0] = pv;
        asm volatile("s_waitcnt lgkmcnt(0)" ::: "memory");
        __builtin_amdgcn_sched_barrier(0);

        int label = labels[b];
        float4 tq = *(const float4*)&logQT[(size_t)label * 256 + c0];

        float prefix = 1.f;
#pragma unroll
        for (int d = 0; d < 6; ++d) {
            int node = (1 << d) - 1 + (lane >> (6 - d));
            float g = psh[w][node];
            prefix *= ((lane >> (5 - d)) & 1) ? g : (1.f - g);
        }
        float g6  = psh[w][63 + lane];
        float p60 = prefix * (1.f - g6), p61 = prefix * g6;
        float g7a = psh[w][127 + 2 * lane];
        float g7b = psh[w][128 + 2 * lane];
        float f0 = p60 * (1.f - g7a), f1 = p60 * g7a;
        float f2 = p61 * (1.f - g7b), f3 = p61 * g7b;

        float lsum = f0 * tq.x + f1 * tq.y + f2 * tq.z + f3 * tq.w;

        float best = f0; int bestIdx = c0;
        if (f1 > best) { best = f1; bestIdx = c0 + 1; }
        if (f2 > best) { best = f2; bestIdx = c0 + 2; }
        if (f3 > best) { best = f3; bestIdx = c0 + 3; }

        for (int sft = 32; sft; sft >>= 1) lsum += __shfl_xor(lsum, sft);
        for (int sft = 32; sft; sft >>= 1) {
            float ov = __shfl_xor(best, sft);
            int   oi = __shfl_xor(bestIdx, sft);
            if (ov > best || (ov == best && oi < bestIdx)) { best = ov; bestIdx = oi; }
        }
        lossAcc += lsum;

        {
            int n = lane;
            float f = 1.f;
            int cur = n;
            while (cur > 0) {
                int par = (cur - 1) >> 1;
                float g = psh[w][par];
                f *= (cur == 2 * par + 2) ? g : (1.f - g);
                cur = par;
            }
            aPI0 += psh[w][n] * f;
            aI0  += f;
        }
        if (lane < 63) {
            int n = lane + 64;
            float f = 1.f;
            int cur = n;
            while (cur > 0) {
                int par = (cur - 1) >> 1;
                float g = psh[w][par];
                f *= (cur == 2 * par + 2) ? g : (1.f - g);
                cur = par;
            }
            aPI1 += psh[w][n] * f;
            aI1  += f;
        }

        const float* qrow = Q + (size_t)bestIdx * 100;
        float* orow = out + 1 + (size_t)b * 100;
        orow[lane] = qrow[lane];
        if (lane < 36) orow[64 + lane] = qrow[64 + lane];
    }

    redPI[w][lane] = aPI0;           redI[w][lane] = aI0;
    redPI[w][64 + lane] = (lane < 63) ? aPI1 : 0.f;
    redI [w][64 + lane] = (lane < 63) ? aI1  : 0.f;
    if (lane == 0) lossw[w] = lossAcc;
    __syncthreads();
    if (tid < 127) {
        float sPI = redPI[0][tid] + redPI[1][tid] + redPI[2][tid] + redPI[3][tid];
        float sI  = redI [0][tid] + redI [1][tid] + redI [2][tid] + redI [3][tid];
        atomicAdd(&accum[1 + tid],   sPI);
        atomicAdd(&accum[128 + tid], sI);
    }
    if (tid == 128) {
        atomicAdd(&accum[0], lossw[0] + lossw[1] + lossw[2] + lossw[3]);
    }
}

// ---------------- kernel: finalize scalars ----------------
__global__ __launch_bounds__(128) void k_final(const float* __restrict__ accum,
                                               float* __restrict__ out)
{
    __shared__ float s[128];
    int t = threadIdx.x;
    float term = 0.f;
    if (t < 127) {
        float a = accum[1 + t] / accum[128 + t];
        int depth = 32 - __clz(t + 1);
        float lmbda = 0.1f * exp2f(-(float)depth);
        term = -lmbda * 0.5f * (logf(a) + log1pf(-a));
    }
    s[t] = term;
    __syncthreads();
    if (t == 0) {
        float c = 0.f;
        for (int i = 0; i < 127; ++i) c += s[i];
        out[819201] = c;
        out[0] = -accum[0] / 8192.0f;
    }
}

// ---------------- launcher ----------------
extern "C" void kernel_launch(void* const* d_in, const int* in_sizes, int n_in,
                              void* d_out, int out_size, void* d_ws, size_t ws_size,
                              hipStream_t stream)
{
    const float* x      = (const float*)d_in[0];
    const int*   labels = (const int*)  d_in[1];
    const float* W      = (const float*)d_in[2];
    const float* bias   = (const float*)d_in[3];
    const float* beta   = (const float*)d_in[4];
    const float* leaf   = (const float*)d_in[5];
    float* out = (float*)d_out;
    float* ws  = (float*)d_ws;

    float*          accum = ws;
    float*          logQT = ws + OFF_LOGQT;
    float*          Q     = ws + OFF_Q;
    unsigned short* whi   = (unsigned short*)(ws + OFF_WHI);
    unsigned short* wlo   = (unsigned short*)(ws + OFF_WLO);
    unsigned short* xhi   = (unsigned short*)(ws + OFF_XHI);
    unsigned short* xlo   = (unsigned short*)(ws + OFF_XLO);

    auto needN = [](int k) { return (size_t)(OFF_PART_NEW + (size_t)k * PART_STRIDE) * sizeof(float); };
    auto needO = [](int k) { return (size_t)(OFF_PART_OLD + (size_t)k * PART_STRIDE) * sizeof(float); };

    int mode, ksplit;
    if      (ws_size >= needN(4)) { mode = 2; ksplit = 4; }
    else if (ws_size >= needN(2)) { mode = 2; ksplit = 2; }
    else if (ws_size >= needN(1)) { mode = 2; ksplit = 1; }
    else if (ws_size >= needO(4)) { mode = 1; ksplit = 4; }
    else if (ws_size >= needO(2)) { mode = 1; ksplit = 2; }
    else                          { mode = 1; ksplit = 1; }

    float* part = ws + (mode == 2 ? OFF_PART_NEW : OFF_PART_OLD);
    const int nxblk = (mode == 2) ? 8192 : 0;

    k_prep<<<nxblk + 320, 256, 0, stream>>>(x, xhi, xlo, nxblk, W, whi, wlo, leaf, logQT, Q, accum);
    if (mode == 2) {
        k_gemm2<<<dim3(128, 1, ksplit), 256, 0, stream>>>(xhi, xlo, whi, wlo, part, 32 / ksplit);
    } else {
        k_gemm_fb<<<dim3(64, 2, ksplit), 256, 0, stream>>>(x, whi, wlo, part, 32 / ksplit);
    }
    k_tree<<<512, 256, 0, stream>>>(part, ksplit, bias, beta, labels, logQT, Q, accum, out);
    k_final<<<1, 128, 0, stream>>>(accum, out);
}

// Round 9
// 163.226 us; speedup vs baseline: 1.8708x; 1.0951x over previous
//
#include <hip/hip_runtime.h>
#include <math.h>

typedef __attribute__((ext_vector_type(4)))  short short4v;
typedef __attribute__((ext_vector_type(8)))  short short8v;
typedef __attribute__((ext_vector_type(4)))  float f32x4;

// ---------------- ws layout (float units) ----------------
// accum[0..255]: [0]=loss, [1..127]=sum p*inner, [128..254]=sum inner
// logQT [100][256] ; Q [256][100]
// whi/wlo (ushort) [256][2048]  -- stored CHUNK-SWIZZLED: within each 64-col
//   block, 8-short chunk index ^= (row & 7)  (self-inverse; matches LDS reads)
// part[z] [8192][256] fp32, z < ksplit
#define OFF_LOGQT 256
#define OFF_Q     25856
#define OFF_WHI   51456
#define OFF_WLO   313600
#define OFF_PART  575744
#define PART_STRIDE 2097152         // 8192*256 floats

__device__ __forceinline__ unsigned short f2bf(float f) {   // RNE to bf16 bits
    unsigned int b = __float_as_uint(f);
    unsigned int r = (b + 0x7FFFu + ((b >> 16) & 1u)) >> 16;
    return (unsigned short)r;
}
__device__ __forceinline__ float bf2f(unsigned short u) {
    return __uint_as_float(((unsigned int)u) << 16);
}
__device__ __forceinline__ void gl16(const void* g, void* l) {
    __builtin_amdgcn_global_load_lds(
        (const __attribute__((address_space(1))) unsigned int*)g,
        (__attribute__((address_space(3))) unsigned int*)l, 16, 0, 0);
}

// ---------------- kernel: prep = W->hl (swizzled) + log_softmax + zero ----------------
// blocks 0..255: W conversion (block 0 also zeroes accum); 256..319: log_softmax
__global__ __launch_bounds__(256) void k_prep(const float* __restrict__ W,
                                              unsigned short* __restrict__ whi,
                                              unsigned short* __restrict__ wlo,
                                              const float* __restrict__ lp,
                                              float* __restrict__ logQT,
                                              float* __restrict__ Q,
                                              float* __restrict__ accum)
{
    const int bx = blockIdx.x, tid = threadIdx.x;
    if (bx < 256) {
        if (bx == 0) accum[tid] = 0.f;
        int g = (bx * 256 + tid) * 8;
        int row = g >> 11;
        int c   = g & 2047;
        int sc  = c ^ ((row & 7) << 3);          // chunk swizzle (8-short granular)
        unsigned short h[8], l[8];
        if (row < 255) {
            const float* src = W + (size_t)row * 2048 + c;
            float4 v0 = *(const float4*)src;
            float4 v1 = *(const float4*)(src + 4);
            float vv[8] = {v0.x, v0.y, v0.z, v0.w, v1.x, v1.y, v1.z, v1.w};
#pragma unroll
            for (int j = 0; j < 8; ++j) {
                h[j] = f2bf(vv[j]);
                l[j] = f2bf(vv[j] - bf2f(h[j]));
            }
        } else {
#pragma unroll
            for (int j = 0; j < 8; ++j) { h[j] = 0; l[j] = 0; }
        }
        size_t dst = (size_t)row * 2048 + sc;
#pragma unroll
        for (int j = 0; j < 8; ++j) { whi[dst + j] = h[j]; wlo[dst + j] = l[j]; }
    } else {
        int w = tid >> 6, lane = tid & 63;
        int r = (bx - 256) * 4 + w;
        float v0 = (lane < 100)      ? lp[r * 100 + lane]      : -INFINITY;
        float v1 = (lane + 64 < 100) ? lp[r * 100 + lane + 64] : -INFINITY;
        float m = fmaxf(v0, v1);
        for (int s = 32; s; s >>= 1) m = fmaxf(m, __shfl_xor(m, s));
        float e = 0.f;
        if (lane < 100)      e += expf(v0 - m);
        if (lane + 64 < 100) e += expf(v1 - m);
        for (int s = 32; s; s >>= 1) e += __shfl_xor(e, s);
        float logZ = m + logf(e);
        if (lane < 100) {
            float lq = v0 - logZ;
            Q[r * 100 + lane] = expf(lq);
            logQT[lane * 256 + r] = lq;
        }
        if (lane + 64 < 100) {
            float lq = v1 - logZ;
            Q[r * 100 + lane + 64] = expf(lq);
            logQT[(lane + 64) * 256 + r] = lq;
        }
    }
}

// ---------------- kernel: split-bf16 MFMA GEMM, swizzled LDS ----------------
// BM=64, BN=256, BK=64; 4 waves, wave-tile 64x64; LDS 80KB -> 2 blocks/CU.
// A: fp32 reg-load + convert + swizzled ds_write. B: gl16 from pre-swizzled whi/wlo.
// All LDS tiles [rows][64] shorts; element (r,c) lives at r*64 + (c ^ ((r&7)<<3)).
__global__ __launch_bounds__(256, 2) void k_gemm3(const float* __restrict__ x,
                                                  const unsigned short* __restrict__ whi,
                                                  const unsigned short* __restrict__ wlo,
                                                  float* __restrict__ part,
                                                  int ksteps)
{
    __shared__ __align__(16) unsigned short Ah[64 * 64];
    __shared__ __align__(16) unsigned short Al[64 * 64];
    __shared__ __align__(16) unsigned short Bh[256 * 64];
    __shared__ __align__(16) unsigned short Bl[256 * 64];

    const int tid = threadIdx.x;
    const int w = tid >> 6, lane = tid & 63;
    const int r16 = lane & 15, hb = lane >> 4;
    const int row0 = blockIdx.x * 64;
    const int kz = blockIdx.z;
    float* pdst = part + (size_t)kz * PART_STRIDE;

    f32x4 acc[4][4] = {};
    float4 aR[4];

    for (int s = 0; s < ksteps; ++s) {
        const int k0 = (kz * ksteps + s) * 64;
        // A: fp32 global -> regs (4 float4/thread)
#pragma unroll
        for (int it = 0; it < 4; ++it) {
            int ch = it * 256 + tid;
            int r = ch >> 4, c = (ch & 15) * 4;
            aR[it] = *(const float4*)(x + (size_t)(row0 + r) * 2048 + k0 + c);
        }
        // B: async global->LDS, source pre-swizzled so linear writes match reads
#pragma unroll
        for (int it = 0; it < 8; ++it) {
            int ch = it * 256 + tid;
            int r = ch >> 3, c = (ch & 7) * 8;
            gl16(whi + (size_t)r * 2048 + k0 + c, &Bh[ch * 8]);
            gl16(wlo + (size_t)r * 2048 + k0 + c, &Bl[ch * 8]);
        }
        // A: convert hi/lo + swizzled ds_write
#pragma unroll
        for (int it = 0; it < 4; ++it) {
            int ch = it * 256 + tid;
            int r = ch >> 4, c = (ch & 15) * 4;
            int sc = c ^ ((r & 7) << 3);            // 4-short write stays in-chunk
            float vv[4] = {aR[it].x, aR[it].y, aR[it].z, aR[it].w};
            short4v hv, lv;
#pragma unroll
            for (int j = 0; j < 4; ++j) {
                unsigned short hbv = f2bf(vv[j]);
                hv[j] = (short)hbv;
                lv[j] = (short)f2bf(vv[j] - bf2f(hbv));
            }
            *(short4v*)&Ah[r * 64 + sc] = hv;
            *(short4v*)&Al[r * 64 + sc] = lv;
        }
        __syncthreads();                            // drains vmcnt + lgkm
#pragma unroll
        for (int kk = 0; kk < 2; ++kk) {
            const int kc = kk * 32 + hb * 8;
            short8v ah[4], al[4];
#pragma unroll
            for (int fm = 0; fm < 4; ++fm) {
                int r = fm * 16 + r16;
                int idx = r * 64 + (kc ^ ((r & 7) << 3));
                ah[fm] = *(const short8v*)&Ah[idx];
                al[fm] = *(const short8v*)&Al[idx];
            }
#pragma unroll
            for (int fn = 0; fn < 4; ++fn) {
                int br = w * 64 + fn * 16 + r16;
                int bidx = br * 64 + (kc ^ ((br & 7) << 3));
                short8v bhh = *(const short8v*)&Bh[bidx];
                short8v bll = *(const short8v*)&Bl[bidx];
#pragma unroll
                for (int fm = 0; fm < 4; ++fm) {
                    acc[fm][fn] = __builtin_amdgcn_mfma_f32_16x16x32_bf16(ah[fm], bhh, acc[fm][fn], 0, 0, 0);
                    acc[fm][fn] = __builtin_amdgcn_mfma_f32_16x16x32_bf16(ah[fm], bll, acc[fm][fn], 0, 0, 0);
                    acc[fm][fn] = __builtin_amdgcn_mfma_f32_16x16x32_bf16(al[fm], bhh, acc[fm][fn], 0, 0, 0);
                }
            }
        }
        __syncthreads();
    }

#pragma unroll
    for (int fm = 0; fm < 4; ++fm)
#pragma unroll
        for (int fn = 0; fn < 4; ++fn) {
            int col = w * 64 + fn * 16 + r16;
#pragma unroll
            for (int j = 0; j < 4; ++j) {
                int row = row0 + fm * 16 + hb * 4 + j;
                pdst[(size_t)row * 256 + col] = acc[fm][fn][j];
            }
        }
}

// ---------------- kernel: fused sigmoid + tree pass ----------------
// 512 blocks x 256 thr; 4 waves/block, 4 rows/wave, wave-local sync; register accumulators.
__global__ __launch_bounds__(256) void k_tree(const float* __restrict__ part, int npart,
                                              const float* __restrict__ bias,
                                              const float* __restrict__ beta,
                                              const int* __restrict__ labels,
                                              const float* __restrict__ logQT,
                                              const float* __restrict__ Q,
                                              float* __restrict__ accum,
                                              float* __restrict__ out)
{
    __shared__ float psh[4][256];
    __shared__ float redPI[4][128];
    __shared__ float redI[4][128];
    __shared__ float lossw[4];
    const int tid = threadIdx.x;
    const int w = tid >> 6, lane = tid & 63;
    const int c0 = lane * 4;

    float4 bi, be;
    if (lane < 63) {
        bi = *(const float4*)&bias[c0];
        be = *(const float4*)&beta[c0];
    } else {
        bi = make_float4(bias[252], bias[253], bias[254], 0.f);
        be = make_float4(beta[252], beta[253], beta[254], 0.f);
    }

    float aPI0 = 0.f, aPI1 = 0.f, aI0 = 0.f, aI1 = 0.f, lossAcc = 0.f;

    for (int rr = 0; rr < 4; ++rr) {
        int b = blockIdx.x * 16 + w * 4 + rr;

        float4 s = make_float4(0.f, 0.f, 0.f, 0.f);
        for (int z = 0; z < npart; ++z) {
            float4 v = *(const float4*)&part[(size_t)z * PART_STRIDE + (size_t)b * 256 + c0];
            s.x += v.x; s.y += v.y; s.z += v.z; s.w += v.w;
        }
        float4 pv;
        pv.x = 1.f / (1.f + expf(-be.x * (s.x + bi.x)));
        pv.y = 1.f / (1.f + expf(-be.y * (s.y + bi.y)));
        pv.z = 1.f / (1.f + expf(-be.z * (s.z + bi.z)));
        pv.w = 1.f / (1.f + expf(-be.w * (s.w + bi.w)));
        *(float4*)&psh[w][c0] = pv;
        asm volatile("s_waitcnt lgkmcnt(0)" ::: "memory");
        __builtin_amdgcn_sched_barrier(0);

        int label = labels[b];
        float4 tq = *(const float4*)&logQT[(size_t)label * 256 + c0];

        float prefix = 1.f;
#pragma unroll
        for (int d = 0; d < 6; ++d) {
            int node = (1 << d) - 1 + (lane >> (6 - d));
            float g = psh[w][node];
            prefix *= ((lane >> (5 - d)) & 1) ? g : (1.f - g);
        }
        float g6  = psh[w][63 + lane];
        float p60 = prefix * (1.f - g6), p61 = prefix * g6;
        float g7a = psh[w][127 + 2 * lane];
        float g7b = psh[w][128 + 2 * lane];
        float f0 = p60 * (1.f - g7a), f1 = p60 * g7a;
        float f2 = p61 * (1.f - g7b), f3 = p61 * g7b;

        float lsum = f0 * tq.x + f1 * tq.y + f2 * tq.z + f3 * tq.w;

        float best = f0; int bestIdx = c0;
        if (f1 > best) { best = f1; bestIdx = c0 + 1; }
        if (f2 > best) { best = f2; bestIdx = c0 + 2; }
        if (f3 > best) { best = f3; bestIdx = c0 + 3; }

        for (int sft = 32; sft; sft >>= 1) lsum += __shfl_xor(lsum, sft);
        for (int sft = 32; sft; sft >>= 1) {
            float ov = __shfl_xor(best, sft);
            int   oi = __shfl_xor(bestIdx, sft);
            if (ov > best || (ov == best && oi < bestIdx)) { best = ov; bestIdx = oi; }
        }
        lossAcc += lsum;

        {
            int n = lane;
            float f = 1.f;
            int cur = n;
            while (cur > 0) {
                int par = (cur - 1) >> 1;
                float g = psh[w][par];
                f *= (cur == 2 * par + 2) ? g : (1.f - g);
                cur = par;
            }
            aPI0 += psh[w][n] * f;
            aI0  += f;
        }
        if (lane < 63) {
            int n = lane + 64;
            float f = 1.f;
            int cur = n;
            while (cur > 0) {
                int par = (cur - 1) >> 1;
                float g = psh[w][par];
                f *= (cur == 2 * par + 2) ? g : (1.f - g);
                cur = par;
            }
            aPI1 += psh[w][n] * f;
            aI1  += f;
        }

        const float* qrow = Q + (size_t)bestIdx * 100;
        float* orow = out + 1 + (size_t)b * 100;
        orow[lane] = qrow[lane];
        if (lane < 36) orow[64 + lane] = qrow[64 + lane];
    }

    redPI[w][lane] = aPI0;           redI[w][lane] = aI0;
    redPI[w][64 + lane] = (lane < 63) ? aPI1 : 0.f;
    redI [w][64 + lane] = (lane < 63) ? aI1  : 0.f;
    if (lane == 0) lossw[w] = lossAcc;
    __syncthreads();
    if (tid < 127) {
        float sPI = redPI[0][tid] + redPI[1][tid] + redPI[2][tid] + redPI[3][tid];
        float sI  = redI [0][tid] + redI [1][tid] + redI [2][tid] + redI [3][tid];
        atomicAdd(&accum[1 + tid],   sPI);
        atomicAdd(&accum[128 + tid], sI);
    }
    if (tid == 128) {
        atomicAdd(&accum[0], lossw[0] + lossw[1] + lossw[2] + lossw[3]);
    }
}

// ---------------- kernel: finalize scalars ----------------
__global__ __launch_bounds__(128) void k_final(const float* __restrict__ accum,
                                               float* __restrict__ out)
{
    __shared__ float s[128];
    int t = threadIdx.x;
    float term = 0.f;
    if (t < 127) {
        float a = accum[1 + t] / accum[128 + t];
        int depth = 32 - __clz(t + 1);
        float lmbda = 0.1f * exp2f(-(float)depth);
        term = -lmbda * 0.5f * (logf(a) + log1pf(-a));
    }
    s[t] = term;
    __syncthreads();
    if (t == 0) {
        float c = 0.f;
        for (int i = 0; i < 127; ++i) c += s[i];
        out[819201] = c;
        out[0] = -accum[0] / 8192.0f;
    }
}

// ---------------- launcher ----------------
extern "C" void kernel_launch(void* const* d_in, const int* in_sizes, int n_in,
                              void* d_out, int out_size, void* d_ws, size_t ws_size,
                              hipStream_t stream)
{
    const float* x      = (const float*)d_in[0];
    const int*   labels = (const int*)  d_in[1];
    const float* W      = (const float*)d_in[2];
    const float* bias   = (const float*)d_in[3];
    const float* beta   = (const float*)d_in[4];
    const float* leaf   = (const float*)d_in[5];
    float* out = (float*)d_out;
    float* ws  = (float*)d_ws;

    float*          accum = ws;
    float*          logQT = ws + OFF_LOGQT;
    float*          Q     = ws + OFF_Q;
    unsigned short* whi   = (unsigned short*)(ws + OFF_WHI);
    unsigned short* wlo   = (unsigned short*)(ws + OFF_WLO);
    float*          part  = ws + OFF_PART;

    auto need = [](int k) { return (size_t)(OFF_PART + (size_t)k * PART_STRIDE) * sizeof(float); };
    int ksplit = (ws_size >= need(4)) ? 4 : (ws_size >= need(2)) ? 2 : 1;

    k_prep<<<320, 256, 0, stream>>>(W, whi, wlo, leaf, logQT, Q, accum);
    k_gemm3<<<dim3(128, 1, ksplit), 256, 0, stream>>>(x, whi, wlo, part, 32 / ksplit);
    k_tree<<<512, 256, 0, stream>>>(part, ksplit, bias, beta, labels, logQT, Q, accum, out);
    k_final<<<1, 128, 0, stream>>>(accum, out);
}